// Round 1
// 106.978 us; speedup vs baseline: 1.1592x; 1.1592x over previous
//
#include <hip/hip_runtime.h>
#include <hip/hip_bf16.h>

#define B_N  4096
#define K_D  1024
#define TILE 128
#define BK   64
#define NT   (B_N / TILE)            // 32 tile-rows
#define NBLK (NT * (NT + 1) / 2)     // 528 upper-triangular tiles

typedef __bf16 bf16x8 __attribute__((ext_vector_type(8)));
typedef float  f32x4  __attribute__((ext_vector_type(4)));

// round-to-nearest-even float -> bf16 bits (inputs are finite normals; no NaN path needed)
__device__ __forceinline__ unsigned short f2bf(float x) {
    union { float f; unsigned int u; } v; v.f = x;
    unsigned int r = v.u + 0x7fffu + ((v.u >> 16) & 1u);
    return (unsigned short)(r >> 16);
}

// One block (256 threads) per row: compute L2 norm, write bf16 normalized row.
// Also zeroes rowsum[row] (and possum) so no separate memset node is needed.
__global__ void normalize_bf16(const float* __restrict__ f, unsigned short* __restrict__ fnb,
                               float* __restrict__ rowsum) {
    const int row = blockIdx.x;
    const int tid = threadIdx.x;
    float4 v = ((const float4*)(f + (size_t)row * K_D))[tid];
    float s = v.x * v.x + v.y * v.y + v.z * v.z + v.w * v.w;
#pragma unroll
    for (int m = 1; m < 64; m <<= 1) s += __shfl_xor(s, m, 64);
    __shared__ float wsum[4];
    if ((tid & 63) == 0) wsum[tid >> 6] = s;
    __syncthreads();
    float tot = wsum[0] + wsum[1] + wsum[2] + wsum[3];
    float scale = 1.0f / fmaxf(sqrtf(tot), 1e-12f);
    ushort4 o;
    o.x = f2bf(v.x * scale); o.y = f2bf(v.y * scale);
    o.z = f2bf(v.z * scale); o.w = f2bf(v.w * scale);
    ((ushort4*)(fnb + (size_t)row * K_D))[tid] = o;
    if (tid == 0) rowsum[row] = 0.0f;
    if (row == 0 && tid == 1) rowsum[B_N] = 0.0f;   // possum slot
}

// Upper-triangular 128x128 tiles of sim = fn*fn^T (symmetric). Each off-diagonal
// tile (bi<bj) is computed once and credited twice: row sums -> rowsum[row-block],
// column sums (quad-reduce) -> rowsum[col-block], pospart*2. Diagonal tiles once.
// 4 waves in 2x2; each wave owns a 64x64 quadrant = 4x4 fragments of 16x16x32 bf16 MFMA.
__global__ void gemm_exp_reduce(const unsigned short* __restrict__ fnb,
                                const int* __restrict__ labels,
                                float* __restrict__ rowsum,
                                float* __restrict__ possum) {
    __shared__ __align__(16) unsigned short As[TILE * BK]; // 16 KB
    __shared__ __align__(16) unsigned short Bs[TILE * BK]; // 16 KB
    __shared__ int   rlab[TILE];
    __shared__ int   clab[TILE];
    __shared__ float posred[4];

    // triangular decode: blockIdx.x -> (bi, bj) with bi <= bj
    int t  = blockIdx.x;
    int bi = 0;
    while (t >= NT - bi) { t -= NT - bi; ++bi; }
    const int  bj   = bi + t;
    const bool diag = (bi == bj);

    const int row0 = bi * TILE, col0 = bj * TILE;
    const int tid  = threadIdx.x;
    const int lane = tid & 63, wave = tid >> 6;
    const int wr = wave >> 1, wc = wave & 1;
    const int quad = lane >> 4, l15 = lane & 15;

    if (tid < TILE) rlab[tid] = labels[row0 + tid];
    else            clab[tid - TILE] = labels[col0 + tid - TILE];

    f32x4 acc[4][4];
#pragma unroll
    for (int i = 0; i < 4; ++i)
#pragma unroll
        for (int j = 0; j < 4; ++j) {
            f32x4 z = {0.f, 0.f, 0.f, 0.f};
            acc[i][j] = z;
        }

    for (int k0 = 0; k0 < K_D; k0 += BK) {
        // Stage A (rows row0..+127) and B (rows col0..+127) as [128][64] bf16.
        // Flat chunk c = it*256+tid covers elements [c*8, c*8+8): LDS dst is
        // contiguous in lane order, as global_load_lds requires.
#pragma unroll
        for (int it = 0; it < 4; ++it) {
            int c  = it * 256 + tid;
            int r  = c >> 3;
            int cc = (c & 7) << 3;
            __builtin_amdgcn_global_load_lds(
                (const unsigned int*)(fnb + (size_t)(row0 + r) * K_D + k0 + cc),
                (unsigned int*)&As[c * 8], 16, 0, 0);
            if (!diag)
                __builtin_amdgcn_global_load_lds(
                    (const unsigned int*)(fnb + (size_t)(col0 + r) * K_D + k0 + cc),
                    (unsigned int*)&Bs[c * 8], 16, 0, 0);
        }
        __syncthreads();

        const unsigned short* Bsrc = diag ? As : Bs;
#pragma unroll
        for (int kk = 0; kk < BK; kk += 32) {
            bf16x8 af[4], bf[4];
#pragma unroll
            for (int fr = 0; fr < 4; ++fr)
                af[fr] = *(const bf16x8*)&As[(wr * 64 + fr * 16 + l15) * BK + kk + quad * 8];
#pragma unroll
            for (int fc = 0; fc < 4; ++fc)
                bf[fc] = *(const bf16x8*)&Bsrc[(wc * 64 + fc * 16 + l15) * BK + kk + quad * 8];
#pragma unroll
            for (int fr = 0; fr < 4; ++fr)
#pragma unroll
                for (int fc = 0; fc < 4; ++fc)
                    acc[fr][fc] = __builtin_amdgcn_mfma_f32_16x16x32_bf16(
                        af[fr], bf[fc], acc[fr][fc], 0, 0, 0);
        }
        __syncthreads();
    }

    // Epilogue. C/D layout (m89/m91-verified): col = lane&15, row = quad*4 + reg.
    float pospart = 0.0f;
    float cs[4] = {0.f, 0.f, 0.f, 0.f};   // per-fc column sums (lane's column, over fr,r)
#pragma unroll
    for (int fr = 0; fr < 4; ++fr) {
        float rp[4] = {0.f, 0.f, 0.f, 0.f};
#pragma unroll
        for (int fc = 0; fc < 4; ++fc) {
            int c    = wc * 64 + fc * 16 + l15;
            int gcol = col0 + c;
            int cl   = clab[c];
#pragma unroll
            for (int r = 0; r < 4; ++r) {
                int rr   = wr * 64 + fr * 16 + quad * 4 + r;
                int grow = row0 + rr;
                float e  = (grow == gcol) ? 0.0f : __expf(acc[fr][fc][r] * 10.0f);
                rp[r] += e;
                cs[fc] += e;
                pospart += (rlab[rr] == cl) ? e : 0.0f;
            }
        }
        // row sums: reduce across the 16 columns (lanes sharing a quad)
#pragma unroll
        for (int r = 0; r < 4; ++r) {
            float v = rp[r];
            v += __shfl_xor(v, 1, 64);
            v += __shfl_xor(v, 2, 64);
            v += __shfl_xor(v, 4, 64);
            v += __shfl_xor(v, 8, 64);
            if (l15 == 0)
                atomicAdd(&rowsum[row0 + wr * 64 + fr * 16 + quad * 4 + r], v);
        }
    }
    if (!diag) {
        // column sums: reduce across the 4 quads (rows of this wave's 64-row band)
#pragma unroll
        for (int fc = 0; fc < 4; ++fc) {
            float v = cs[fc];
            v += __shfl_xor(v, 16, 64);
            v += __shfl_xor(v, 32, 64);
            if (quad == 0)
                atomicAdd(&rowsum[col0 + wc * 64 + fc * 16 + l15], v);
        }
        pospart *= 2.0f;   // mirror tile (bj,bi) contributes identically
    }
#pragma unroll
    for (int m = 1; m < 64; m <<= 1) pospart += __shfl_xor(pospart, m, 64);
    if (lane == 0) posred[wave] = pospart;
    __syncthreads();
    if (tid == 0)
        atomicAdd(possum, posred[0] + posred[1] + posred[2] + posred[3]);
}

__global__ void finalize(const float* __restrict__ rowsum,
                         const float* __restrict__ possum,
                         float* __restrict__ out) {
    const int tid = threadIdx.x;
    float s = 0.f;
    for (int i = tid; i < B_N; i += 256) s += logf(rowsum[i]);
#pragma unroll
    for (int m = 1; m < 64; m <<= 1) s += __shfl_xor(s, m, 64);
    __shared__ float w[4];
    if ((tid & 63) == 0) w[tid >> 6] = s;
    __syncthreads();
    if (tid == 0) {
        float tot = w[0] + w[1] + w[2] + w[3];
        // loss = mean_i log(rowsum_i)  -  log(possum)
        out[0] = tot / (float)B_N - logf(possum[0]);
    }
}

extern "C" void kernel_launch(void* const* d_in, const int* in_sizes, int n_in,
                              void* d_out, int out_size, void* d_ws, size_t ws_size,
                              hipStream_t stream) {
    const float* features = (const float*)d_in[0];
    const int*   targets  = (const int*)d_in[1];
    float*       out      = (float*)d_out;

    // workspace layout: [bf16 fn: 8 MB][rowsum: 4096 f32][possum: 1 f32]
    unsigned short* fnb    = (unsigned short*)d_ws;
    float*          rowsum = (float*)((char*)d_ws + (size_t)B_N * K_D * sizeof(unsigned short));
    float*          possum = rowsum + B_N;

    normalize_bf16<<<B_N, 256, 0, stream>>>(features, fnb, rowsum);
    gemm_exp_reduce<<<NBLK, 256, 0, stream>>>(fnb, targets, rowsum, possum);
    finalize<<<1, 256, 0, stream>>>(rowsum, possum, out);
}